// Round 1
// baseline (271.242 us; speedup 1.0000x reference)
//
#include <hip/hip_runtime.h>
#include <math.h>

#define NN 8192
#define FIN 512
#define HD 128
#define CAP 128

// ---------------------------------------------------------------------------
// K1: extract sparse adjacency (deterministic ballot-compaction, no atomics).
// One wave per row; scans the 8192-float row as float4, appends nonzero col
// indices in order via ballot prefix. deg = max(row_sum, 1).
// ---------------------------------------------------------------------------
__global__ __launch_bounds__(64) void k_build_adj(
    const float* __restrict__ adj, int* __restrict__ nbr,
    int* __restrict__ degi, float* __restrict__ degf)
{
    const int i = blockIdx.x;
    const int lane = threadIdx.x;
    const float4* row = (const float4*)(adj + (size_t)i * NN);
    int* lst = nbr + (size_t)i * CAP;
    int cnt = 0;
    for (int it = 0; it < NN / 4 / 64; ++it) {   // 32 iters
        const int v = it * 64 + lane;
        const float4 a = row[v];
        const int j0 = v * 4;
        const float vals[4] = {a.x, a.y, a.z, a.w};
        #pragma unroll
        for (int e = 0; e < 4; ++e) {
            const bool nz = (vals[e] != 0.0f);
            const unsigned long long m = __ballot(nz);
            if (nz) {
                const int p = cnt + (int)__popcll(m & ((1ull << lane) - 1ull));
                if (p < CAP) lst[p] = j0 + e;
            }
            cnt += (int)__popcll(m);
        }
    }
    if (lane == 0) {
        degi[i] = cnt < CAP ? cnt : CAP;
        degf[i] = fmaxf((float)cnt, 1.0f);
    }
}

// ---------------------------------------------------------------------------
// K2/K4: mean aggregation over neighbor lists. dst[i,:] = mean_j x[j,:]
// ---------------------------------------------------------------------------
template<int F, int RPB>
__global__ __launch_bounds__(256) void k_aggregate(
    const float* __restrict__ src, const int* __restrict__ nbr,
    const int* __restrict__ degi, const float* __restrict__ degf,
    float* __restrict__ dst)
{
    constexpr int C4 = F / 4;
    const int sub  = threadIdx.x / C4;
    const int lane = threadIdx.x % C4;
    const int i = blockIdx.x * RPB + sub;
    const int d = degi[i];
    const float inv = 1.0f / degf[i];
    const int* lst = nbr + (size_t)i * CAP;
    float4 s = make_float4(0.f, 0.f, 0.f, 0.f);
    for (int t = 0; t < d; ++t) {
        const int j = lst[t];
        const float4 v = ((const float4*)(src + (size_t)j * F))[lane];
        s.x += v.x; s.y += v.y; s.z += v.z; s.w += v.w;
    }
    s.x *= inv; s.y *= inv; s.z *= inv; s.w *= inv;
    ((float4*)(dst + (size_t)i * F))[lane] = s;
}

// ---------------------------------------------------------------------------
// K3/K5: fused dual-source f32 GEMM:  C = act(A1@W1 + A2@W2 + bias)
// Block tile 32x128, 256 threads, 4x4 micro-tile, K staged in 64-chunks.
// A staged transposed in LDS so compute reads are ds_read_b128.
// ---------------------------------------------------------------------------
template<int RELU>
__global__ __launch_bounds__(256) void k_gemm2src(
    const float* __restrict__ A1, const float* __restrict__ W1, const int nch1,
    const float* __restrict__ A2, const float* __restrict__ W2, const int nch2,
    const float* __restrict__ bias, float* __restrict__ C)
{
    constexpr int TM = 32, TN = 128, KB = 64;
    __shared__ float As[KB][TM];    // [k][row]
    __shared__ float Bs[KB][TN];    // [k][col]

    const int tid  = threadIdx.x;
    const int row0 = blockIdx.x * TM;
    const int rg = tid >> 5;           // 0..7 -> rows rg*4..+3
    const int cg = tid & 31;           // cols cg*4..+3
    const int ar = tid >> 3;           // staging: row 0..31
    const int ak = (tid & 7) * 8;      // staging: k offset (8 floats)
    const int bk = tid >> 5;           // staging: W k-row 0..7 (+8*it)
    const int bc = (tid & 31) * 4;     // staging: W col

    float acc[4][4];
    #pragma unroll
    for (int a = 0; a < 4; ++a)
        #pragma unroll
        for (int b = 0; b < 4; ++b) acc[a][b] = 0.0f;

    const int nch = nch1 + nch2;
    for (int ch = 0; ch < nch; ++ch) {
        const float* A; const float* W; int kc, ldA;
        if (ch < nch1) { A = A1; W = W1; kc = ch * KB;          ldA = nch1 * KB; }
        else           { A = A2; W = W2; kc = (ch - nch1) * KB; ldA = nch2 * KB; }

        __syncthreads();
        {
            const float4 v0 = *(const float4*)(A + (size_t)(row0 + ar) * ldA + kc + ak);
            const float4 v1 = *(const float4*)(A + (size_t)(row0 + ar) * ldA + kc + ak + 4);
            As[ak + 0][ar] = v0.x; As[ak + 1][ar] = v0.y; As[ak + 2][ar] = v0.z; As[ak + 3][ar] = v0.w;
            As[ak + 4][ar] = v1.x; As[ak + 5][ar] = v1.y; As[ak + 6][ar] = v1.z; As[ak + 7][ar] = v1.w;
        }
        #pragma unroll
        for (int it = 0; it < 8; ++it) {
            *(float4*)&Bs[bk + 8 * it][bc] =
                *(const float4*)(W + (size_t)(kc + bk + 8 * it) * TN + bc);
        }
        __syncthreads();

        #pragma unroll
        for (int k = 0; k < KB; ++k) {
            const float4 a4 = *(const float4*)&As[k][rg * 4];
            const float4 b4 = *(const float4*)&Bs[k][cg * 4];
            const float av[4] = {a4.x, a4.y, a4.z, a4.w};
            const float bv[4] = {b4.x, b4.y, b4.z, b4.w};
            #pragma unroll
            for (int a = 0; a < 4; ++a)
                #pragma unroll
                for (int b = 0; b < 4; ++b)
                    acc[a][b] = fmaf(av[a], bv[b], acc[a][b]);
        }
    }

    const float4 bi = *(const float4*)(bias + cg * 4);
    const float bv[4] = {bi.x, bi.y, bi.z, bi.w};
    #pragma unroll
    for (int a = 0; a < 4; ++a) {
        float4 o;
        o.x = acc[a][0] + bv[0];
        o.y = acc[a][1] + bv[1];
        o.z = acc[a][2] + bv[2];
        o.w = acc[a][3] + bv[3];
        if (RELU) {
            o.x = fmaxf(o.x, 0.f); o.y = fmaxf(o.y, 0.f);
            o.z = fmaxf(o.z, 0.f); o.w = fmaxf(o.w, 0.f);
        }
        *(float4*)(C + (size_t)(row0 + rg * 4 + a) * TN + cg * 4) = o;
    }
}

// ---------------------------------------------------------------------------
// K6: y = h2 @ Wd + bd  (K=128, OUT=3), one wave per row, shuffle reduce.
// Stores y padded to float4.
// ---------------------------------------------------------------------------
__global__ __launch_bounds__(64) void k_proj_y(
    const float* __restrict__ h2, const float* __restrict__ Wd,
    const float* __restrict__ bd, float4* __restrict__ y4)
{
    const int i = blockIdx.x;
    const int t = threadIdx.x;  // 0..63
    const float v0 = h2[(size_t)i * HD + t];
    const float v1 = h2[(size_t)i * HD + t + 64];
    float s0 = v0 * Wd[t * 3 + 0] + v1 * Wd[(t + 64) * 3 + 0];
    float s1 = v0 * Wd[t * 3 + 1] + v1 * Wd[(t + 64) * 3 + 1];
    float s2 = v0 * Wd[t * 3 + 2] + v1 * Wd[(t + 64) * 3 + 2];
    #pragma unroll
    for (int off = 32; off > 0; off >>= 1) {
        s0 += __shfl_down(s0, off);
        s1 += __shfl_down(s1, off);
        s2 += __shfl_down(s2, off);
    }
    if (t == 0) y4[i] = make_float4(s0 + bd[0], s1 + bd[1], s2 + bd[2], 0.f);
}

// ---------------------------------------------------------------------------
// K7: out[i,j] = ||y_i - y_j||.  Direct 3-vector diff (exact at diagonal),
// float4 stores -> 1 KiB/wave contiguous.
// ---------------------------------------------------------------------------
__global__ __launch_bounds__(256) void k_cdist(
    const float4* __restrict__ y4, float* __restrict__ out)
{
    const int i  = blockIdx.y;
    const int j0 = (blockIdx.x * 256 + threadIdx.x) * 4;
    const float4 yi = y4[i];
    float4 r;
    #pragma unroll
    for (int e = 0; e < 4; ++e) {
        const float4 a = y4[j0 + e];
        const float dx = yi.x - a.x, dy = yi.y - a.y, dz = yi.z - a.z;
        const float d2 = dx * dx + dy * dy + dz * dz;
        ((float*)&r)[e] = sqrtf(d2);
    }
    *(float4*)(out + (size_t)i * NN + j0) = r;
}

// ---------------------------------------------------------------------------
extern "C" void kernel_launch(void* const* d_in, const int* in_sizes, int n_in,
                              void* d_out, int out_size, void* d_ws, size_t ws_size,
                              hipStream_t stream) {
    const float* x   = (const float*)d_in[0];
    const float* adj = (const float*)d_in[1];
    const float* Wl1 = (const float*)d_in[2];
    const float* Wr1 = (const float*)d_in[3];
    const float* b1  = (const float*)d_in[4];
    const float* Wl2 = (const float*)d_in[5];
    const float* Wr2 = (const float*)d_in[6];
    const float* b2  = (const float*)d_in[7];
    const float* Wd  = (const float*)d_in[8];
    const float* bd  = (const float*)d_in[9];
    float* out = (float*)d_out;

    // ---- workspace layout ----
    char* ws = (char*)d_ws;
    const size_t nbr_b  = (size_t)NN * CAP * 4;    // 4 MB
    const size_t degi_b = (size_t)NN * 4;
    const size_t degf_b = (size_t)NN * 4;
    const size_t y4_b   = (size_t)NN * 16;
    const size_t small_total = nbr_b + degi_b + degf_b + y4_b;

    const size_t agg_b  = (size_t)NN * FIN * 4;    // 16 MB
    const size_t h_b    = (size_t)NN * HD * 4;     // 4 MB
    const size_t big_total = agg_b + 3 * h_b;      // 28 MB

    int*   nbr  = (int*)(ws);
    int*   degi = (int*)(ws + nbr_b);
    float* degf = (float*)(ws + nbr_b + degi_b);
    float4* y4  = (float4*)(ws + nbr_b + degi_b + degf_b);

    // Big intermediates: in ws if it fits, else carve from d_out (256 MB,
    // only written by the final cdist kernel which reads only y4).
    char* big = (ws_size >= small_total + big_total) ? (ws + small_total)
                                                     : (char*)d_out;
    float* agg  = (float*)(big);
    float* h    = (float*)(big + agg_b);
    float* agg2 = (float*)(big + agg_b + h_b);
    float* h2   = (float*)(big + agg_b + 2 * h_b);

    // ---- pipeline ----
    k_build_adj<<<NN, 64, 0, stream>>>(adj, nbr, degi, degf);

    k_aggregate<FIN, 2><<<NN / 2, 256, 0, stream>>>(x, nbr, degi, degf, agg);

    k_gemm2src<1><<<NN / 32, 256, 0, stream>>>(agg, Wl1, FIN / 64,
                                               x,   Wr1, FIN / 64, b1, h);

    k_aggregate<HD, 8><<<NN / 8, 256, 0, stream>>>(h, nbr, degi, degf, agg2);

    k_gemm2src<0><<<NN / 32, 256, 0, stream>>>(agg2, Wl2, HD / 64,
                                               h,    Wr2, HD / 64, b2, h2);

    k_proj_y<<<NN, 64, 0, stream>>>(h2, Wd, bd, y4);

    k_cdist<<<dim3(NN / 1024, NN), 256, 0, stream>>>(y4, out);
}

// Round 2
// 183.905 us; speedup vs baseline: 1.4749x; 1.4749x over previous
//
#include <hip/hip_runtime.h>
#include <math.h>

#define NN 8192
#define FIN 512
#define HD 128
#define CAP 128
#define GEMM_B 512   // blocks 0..511: GEMM; rest: adjacency scan
#define ADJ_B  2048

// ---------------------------------------------------------------------------
// K0: fold decoder into layer-2 weights: Wld = Wl2@Wd, Wrd = Wr2@Wd,
// c = b2@Wd + bd.  wsm layout (float4 units): [0..127]=Wld rows,
// [128..255]=Wrd rows, [256]=c.
// ---------------------------------------------------------------------------
__global__ __launch_bounds__(128) void k_small_w(
    const float* __restrict__ Wl2, const float* __restrict__ Wr2,
    const float* __restrict__ b2, const float* __restrict__ Wd,
    const float* __restrict__ bd, float4* __restrict__ wsm)
{
    const int t = threadIdx.x;
    float l0 = 0, l1 = 0, l2 = 0, r0 = 0, r1 = 0, r2 = 0;
    for (int c = 0; c < HD; ++c) {
        const float w0 = Wd[c * 3 + 0], w1 = Wd[c * 3 + 1], w2 = Wd[c * 3 + 2];
        const float wl = Wl2[t * HD + c];
        const float wr = Wr2[t * HD + c];
        l0 = fmaf(wl, w0, l0); l1 = fmaf(wl, w1, l1); l2 = fmaf(wl, w2, l2);
        r0 = fmaf(wr, w0, r0); r1 = fmaf(wr, w1, r1); r2 = fmaf(wr, w2, r2);
    }
    wsm[t]       = make_float4(l0, l1, l2, 0.f);
    wsm[128 + t] = make_float4(r0, r1, r2, 0.f);
    if (t == 0) {
        float c0 = bd[0], c1 = bd[1], c2 = bd[2];
        for (int c = 0; c < HD; ++c) {
            c0 = fmaf(b2[c], Wd[c * 3 + 0], c0);
            c1 = fmaf(b2[c], Wd[c * 3 + 1], c1);
            c2 = fmaf(b2[c], Wd[c * 3 + 2], c2);
        }
        wsm[256] = make_float4(c0, c1, c2, 0.f);
    }
}

// ---------------------------------------------------------------------------
// K1: heterogeneous kernel.
//   blocks [0,256):    xl = x @ Wl1   (tile 32x128, KB=32)
//   blocks [256,512):  xr = x @ Wr1
//   blocks [512,2560): adjacency scan -> nbr/degi/degf (4 rows/block, 1/wave)
// The VALU-bound GEMM hides under the HBM-bound adj scan.
// ---------------------------------------------------------------------------
__global__ __launch_bounds__(256) void k_fused_gemm_adj(
    const float* __restrict__ x, const float* __restrict__ Wl1,
    const float* __restrict__ Wr1, const float* __restrict__ adj,
    float* __restrict__ xl, float* __restrict__ xr,
    int* __restrict__ nbr, int* __restrict__ degi, float* __restrict__ degf)
{
    if (blockIdx.x < GEMM_B) {
        constexpr int TM = 32, TN = 128, KB = 32;
        __shared__ float As[KB][TM];   // [k][row]
        __shared__ float Bs[KB][TN];   // [k][col]
        const float* W = (blockIdx.x < 256) ? Wl1 : Wr1;
        float* Cout    = (blockIdx.x < 256) ? xl  : xr;
        const int row0 = (blockIdx.x & 255) * TM;
        const int tid = threadIdx.x;
        const int rg = tid >> 5, cg = tid & 31;
        const int ar = tid >> 3, ak = (tid & 7) * 4;
        const int bk = tid >> 5, bc = (tid & 31) * 4;
        float acc[4][4] = {};
        for (int ch = 0; ch < FIN / KB; ++ch) {
            const int kc = ch * KB;
            __syncthreads();
            const float4 va = *(const float4*)(x + (size_t)(row0 + ar) * FIN + kc + ak);
            As[ak + 0][ar] = va.x; As[ak + 1][ar] = va.y;
            As[ak + 2][ar] = va.z; As[ak + 3][ar] = va.w;
            #pragma unroll
            for (int it = 0; it < 4; ++it)
                *(float4*)&Bs[bk + 8 * it][bc] =
                    *(const float4*)(W + (size_t)(kc + bk + 8 * it) * TN + bc);
            __syncthreads();
            #pragma unroll
            for (int k = 0; k < KB; ++k) {
                const float4 a4 = *(const float4*)&As[k][rg * 4];
                const float4 b4 = *(const float4*)&Bs[k][cg * 4];
                const float av[4] = {a4.x, a4.y, a4.z, a4.w};
                const float bv[4] = {b4.x, b4.y, b4.z, b4.w};
                #pragma unroll
                for (int a = 0; a < 4; ++a)
                    #pragma unroll
                    for (int b = 0; b < 4; ++b)
                        acc[a][b] = fmaf(av[a], bv[b], acc[a][b]);
            }
        }
        #pragma unroll
        for (int a = 0; a < 4; ++a)
            *(float4*)(Cout + (size_t)(row0 + rg * 4 + a) * TN + cg * 4) =
                make_float4(acc[a][0], acc[a][1], acc[a][2], acc[a][3]);
    } else {
        const int i = (blockIdx.x - GEMM_B) * 4 + (threadIdx.x >> 6);
        const int lane = threadIdx.x & 63;
        const float4* row = (const float4*)(adj + (size_t)i * NN);
        int* lst = nbr + (size_t)i * CAP;
        int cnt = 0;
        for (int it = 0; it < NN / 4 / 64; ++it) {   // 32 iters
            const int v = it * 64 + lane;
            const float4 a = row[v];
            const int j0 = v * 4;
            const float vals[4] = {a.x, a.y, a.z, a.w};
            #pragma unroll
            for (int e = 0; e < 4; ++e) {
                const bool nz = (vals[e] != 0.0f);
                const unsigned long long m = __ballot(nz);
                if (nz) {
                    const int p = cnt + (int)__popcll(m & ((1ull << lane) - 1ull));
                    if (p < CAP) lst[p] = j0 + e;
                }
                cnt += (int)__popcll(m);
            }
        }
        if (lane == 0) {
            degi[i] = cnt < CAP ? cnt : CAP;
            degf[i] = fmaxf((float)cnt, 1.0f);
        }
    }
}

// ---------------------------------------------------------------------------
// K2: per row i (one 32-lane half-wave):
//   h = relu(mean_j xl[j,:]  + xr[i,:] + b1)   (in registers, 4 cols/lane)
//   u[i] = h @ Wld, v[i] = h @ Wrd             (shuffle-reduced 3-vectors)
// h is never written to memory.
// ---------------------------------------------------------------------------
__global__ __launch_bounds__(256) void k_agg_proj(
    const float* __restrict__ xl, const float* __restrict__ xr,
    const float* __restrict__ b1, const int* __restrict__ nbr,
    const int* __restrict__ degi, const float* __restrict__ degf,
    const float4* __restrict__ wsm, float4* __restrict__ u4,
    float4* __restrict__ v4)
{
    const int hw = threadIdx.x >> 5;
    const int lane = threadIdx.x & 31;
    const int i = blockIdx.x * 8 + hw;
    float4 wld[4], wrd[4];
    #pragma unroll
    for (int e = 0; e < 4; ++e) {
        wld[e] = wsm[lane * 4 + e];
        wrd[e] = wsm[128 + lane * 4 + e];
    }
    const float4 b14 = ((const float4*)b1)[lane];
    const int d = degi[i];
    const float inv = 1.0f / degf[i];
    const int* lst = nbr + (size_t)i * CAP;

    float4 s = make_float4(0.f, 0.f, 0.f, 0.f);
    for (int base = 0; base < d; base += 32) {
        const int jv = (base + lane < d) ? lst[base + lane] : 0;
        const int cnt = min(32, d - base);
        for (int t = 0; t < cnt; ++t) {
            const int j = __shfl(jv, t, 32);
            const float4 v = ((const float4*)xl)[(size_t)j * 32 + lane];
            s.x += v.x; s.y += v.y; s.z += v.z; s.w += v.w;
        }
    }
    const float4 r4 = ((const float4*)xr)[(size_t)i * 32 + lane];
    float h[4];
    h[0] = fmaxf(fmaf(s.x, inv, r4.x + b14.x), 0.f);
    h[1] = fmaxf(fmaf(s.y, inv, r4.y + b14.y), 0.f);
    h[2] = fmaxf(fmaf(s.z, inv, r4.z + b14.z), 0.f);
    h[3] = fmaxf(fmaf(s.w, inv, r4.w + b14.w), 0.f);

    float u0 = h[0]*wld[0].x + h[1]*wld[1].x + h[2]*wld[2].x + h[3]*wld[3].x;
    float u1 = h[0]*wld[0].y + h[1]*wld[1].y + h[2]*wld[2].y + h[3]*wld[3].y;
    float u2 = h[0]*wld[0].z + h[1]*wld[1].z + h[2]*wld[2].z + h[3]*wld[3].z;
    float v0 = h[0]*wrd[0].x + h[1]*wrd[1].x + h[2]*wrd[2].x + h[3]*wrd[3].x;
    float v1 = h[0]*wrd[0].y + h[1]*wrd[1].y + h[2]*wrd[2].y + h[3]*wrd[3].y;
    float v2 = h[0]*wrd[0].z + h[1]*wrd[1].z + h[2]*wrd[2].z + h[3]*wrd[3].z;
    #pragma unroll
    for (int off = 16; off; off >>= 1) {
        u0 += __shfl_xor(u0, off); u1 += __shfl_xor(u1, off); u2 += __shfl_xor(u2, off);
        v0 += __shfl_xor(v0, off); v1 += __shfl_xor(v1, off); v2 += __shfl_xor(v2, off);
    }
    if (lane == 0) {
        u4[i] = make_float4(u0, u1, u2, 0.f);
        v4[i] = make_float4(v0, v1, v2, 0.f);
    }
}

// ---------------------------------------------------------------------------
// K3: y[i] = mean_j u[j] + v[i] + c   (3-wide aggregation, L2-resident)
// ---------------------------------------------------------------------------
__global__ __launch_bounds__(256) void k_ycomb(
    const float4* __restrict__ u4, const float4* __restrict__ v4,
    const int* __restrict__ nbr, const int* __restrict__ degi,
    const float* __restrict__ degf, const float4* __restrict__ wsm,
    float4* __restrict__ y4)
{
    const int hw = threadIdx.x >> 5;
    const int lane = threadIdx.x & 31;
    const int i = blockIdx.x * 8 + hw;
    const int d = degi[i];
    const float inv = 1.0f / degf[i];
    const int* lst = nbr + (size_t)i * CAP;
    float s0 = 0.f, s1 = 0.f, s2 = 0.f;
    for (int base = 0; base + lane < d; base += 32) {
        const float4 u = u4[lst[base + lane]];
        s0 += u.x; s1 += u.y; s2 += u.z;
    }
    #pragma unroll
    for (int off = 16; off; off >>= 1) {
        s0 += __shfl_xor(s0, off); s1 += __shfl_xor(s1, off); s2 += __shfl_xor(s2, off);
    }
    if (lane == 0) {
        const float4 v = v4[i];
        const float4 c = wsm[256];
        y4[i] = make_float4(fmaf(s0, inv, v.x + c.x),
                            fmaf(s1, inv, v.y + c.y),
                            fmaf(s2, inv, v.z + c.z), 0.f);
    }
}

// ---------------------------------------------------------------------------
// K4: out[i,j] = ||y_i - y_j||
// ---------------------------------------------------------------------------
__global__ __launch_bounds__(256) void k_cdist(
    const float4* __restrict__ y4, float* __restrict__ out)
{
    const int i  = blockIdx.y;
    const int j0 = (blockIdx.x * 256 + threadIdx.x) * 4;
    const float4 yi = y4[i];
    float4 r;
    #pragma unroll
    for (int e = 0; e < 4; ++e) {
        const float4 a = y4[j0 + e];
        const float dx = yi.x - a.x, dy = yi.y - a.y, dz = yi.z - a.z;
        ((float*)&r)[e] = sqrtf(dx * dx + dy * dy + dz * dz);
    }
    *(float4*)(out + (size_t)i * NN + j0) = r;
}

// ---------------------------------------------------------------------------
extern "C" void kernel_launch(void* const* d_in, const int* in_sizes, int n_in,
                              void* d_out, int out_size, void* d_ws, size_t ws_size,
                              hipStream_t stream) {
    const float* x   = (const float*)d_in[0];
    const float* adj = (const float*)d_in[1];
    const float* Wl1 = (const float*)d_in[2];
    const float* Wr1 = (const float*)d_in[3];
    const float* b1  = (const float*)d_in[4];
    const float* Wl2 = (const float*)d_in[5];
    const float* Wr2 = (const float*)d_in[6];
    const float* b2  = (const float*)d_in[7];
    const float* Wd  = (const float*)d_in[8];
    const float* bd  = (const float*)d_in[9];
    float* out = (float*)d_out;

    // ---- workspace layout ----
    char* ws = (char*)d_ws;
    const size_t nbr_b  = (size_t)NN * CAP * 4;    // 4 MB
    const size_t degi_b = (size_t)NN * 4;
    const size_t degf_b = (size_t)NN * 4;
    const size_t u_b    = (size_t)NN * 16;
    const size_t wsm_b  = 260 * 16;
    const size_t small_total = nbr_b + degi_b + degf_b + 3 * u_b + wsm_b;
    const size_t xl_b = (size_t)NN * HD * 4;       // 4 MB each

    int*    nbr  = (int*)(ws);
    int*    degi = (int*)(ws + nbr_b);
    float*  degf = (float*)(ws + nbr_b + degi_b);
    float4* u4   = (float4*)(ws + nbr_b + degi_b + degf_b);
    float4* v4   = (float4*)(ws + nbr_b + degi_b + degf_b + u_b);
    float4* y4   = (float4*)(ws + nbr_b + degi_b + degf_b + 2 * u_b);
    float4* wsm  = (float4*)(ws + nbr_b + degi_b + degf_b + 3 * u_b);

    // xl/xr: in ws if it fits, else carve from d_out (dead before k_cdist).
    char* big = (ws_size >= small_total + 2 * xl_b) ? (ws + small_total)
                                                    : (char*)d_out;
    float* xl = (float*)(big);
    float* xr = (float*)(big + xl_b);

    // ---- pipeline ----
    k_small_w<<<1, 128, 0, stream>>>(Wl2, Wr2, b2, Wd, bd, wsm);

    k_fused_gemm_adj<<<GEMM_B + ADJ_B, 256, 0, stream>>>(
        x, Wl1, Wr1, adj, xl, xr, nbr, degi, degf);

    k_agg_proj<<<NN / 8, 256, 0, stream>>>(xl, xr, b1, nbr, degi, degf,
                                           wsm, u4, v4);

    k_ycomb<<<NN / 8, 256, 0, stream>>>(u4, v4, nbr, degi, degf, wsm, y4);

    k_cdist<<<dim3(NN / 1024, NN), 256, 0, stream>>>(y4, out);
}

// Round 4
// 146.883 us; speedup vs baseline: 1.8467x; 1.2521x over previous
//
#include <hip/hip_runtime.h>
#include <math.h>

#define NN 8192
#define FIN 512
#define HD 128
#define CAP 128
#define GEMM_B 512   // blocks [0,512): GEMM; [512,2560): adj scan; 2560: weights
#define ADJ_B  2048

// ---------------------------------------------------------------------------
// K1 "front": heterogeneous kernel, no inter-block communication.
//   blocks [0,256):      xl = x @ Wl1   (tile 32x128, KB=32)
//   blocks [256,512):    xr = x @ Wr1
//   blocks [512,2560):   adjacency scan -> nbr/degi/degf (1 row/wave)
//   block  2560:         fold layer2+decoder weights:
//                        wsm[0..127]=Wl2@Wd rows, [128..255]=Wr2@Wd, [256]=b2@Wd+bd
// The VALU-bound GEMM hides under the HBM-bound adj scan.
// ---------------------------------------------------------------------------
__global__ __launch_bounds__(256) void k_front(
    const float* __restrict__ x, const float* __restrict__ Wl1,
    const float* __restrict__ Wr1, const float* __restrict__ adj,
    const float* __restrict__ Wl2, const float* __restrict__ Wr2,
    const float* __restrict__ b2, const float* __restrict__ Wd,
    const float* __restrict__ bd,
    float* __restrict__ xl, float* __restrict__ xr,
    int* __restrict__ nbr, int* __restrict__ degi, float* __restrict__ degf,
    float4* __restrict__ wsm)
{
    __shared__ float As[32][32];
    __shared__ float Bs[32][128];
    const int tid = threadIdx.x;

    if (blockIdx.x < GEMM_B) {
        // ---------------- GEMM: 32x128 tile, K=512 ----------------
        const float* W = (blockIdx.x < 256) ? Wl1 : Wr1;
        float* Cout    = (blockIdx.x < 256) ? xl  : xr;
        const int row0 = (blockIdx.x & 255) * 32;
        const int rg = tid >> 5, cg = tid & 31;
        const int ar = tid >> 3, ak = (tid & 7) * 4;
        const int bk = tid >> 5, bc = (tid & 31) * 4;
        float acc[4][4] = {};
        for (int ch = 0; ch < FIN / 32; ++ch) {
            const int kc = ch * 32;
            __syncthreads();
            const float4 va = *(const float4*)(x + (size_t)(row0 + ar) * FIN + kc + ak);
            As[ak + 0][ar] = va.x; As[ak + 1][ar] = va.y;
            As[ak + 2][ar] = va.z; As[ak + 3][ar] = va.w;
            #pragma unroll
            for (int it = 0; it < 4; ++it)
                *(float4*)&Bs[bk + 8 * it][bc] =
                    *(const float4*)(W + (size_t)(kc + bk + 8 * it) * HD + bc);
            __syncthreads();
            #pragma unroll
            for (int k = 0; k < 32; ++k) {
                const float4 a4 = *(const float4*)&As[k][rg * 4];
                const float4 b4 = *(const float4*)&Bs[k][cg * 4];
                const float av[4] = {a4.x, a4.y, a4.z, a4.w};
                const float bv[4] = {b4.x, b4.y, b4.z, b4.w};
                #pragma unroll
                for (int a = 0; a < 4; ++a)
                    #pragma unroll
                    for (int b = 0; b < 4; ++b)
                        acc[a][b] = fmaf(av[a], bv[b], acc[a][b]);
            }
        }
        #pragma unroll
        for (int a = 0; a < 4; ++a)
            *(float4*)(Cout + (size_t)(row0 + rg * 4 + a) * HD + cg * 4) =
                make_float4(acc[a][0], acc[a][1], acc[a][2], acc[a][3]);
    } else if (blockIdx.x < GEMM_B + ADJ_B) {
        // ---------------- adjacency scan: 1 row per 64-lane wave ----------
        const int w = tid >> 6, lane = tid & 63;
        const int i = (blockIdx.x - GEMM_B) * 4 + w;
        int* lst = nbr + (size_t)i * CAP;
        const float4* row = (const float4*)(adj + (size_t)i * NN);
        const unsigned long long lmask = (1ull << lane) - 1ull;
        int cnt = 0;
        for (int it = 0; it < NN / 256; ++it) {   // 32 iters, 1 KB/wave each
            const float4 a = row[it * 64 + lane];
            const float vals[4] = {a.x, a.y, a.z, a.w};
            #pragma unroll
            for (int e = 0; e < 4; ++e) {
                const bool nz = (vals[e] != 0.0f);
                const unsigned long long m = __ballot(nz);
                if (nz) {
                    const int p = cnt + (int)__popcll(m & lmask);
                    if (p < CAP) lst[p] = (it * 64 + lane) * 4 + e;
                }
                cnt += (int)__popcll(m);
            }
        }
        if (lane == 0) {
            degi[i] = cnt < CAP ? cnt : CAP;
            degf[i] = fmaxf((float)cnt, 1.0f);
        }
    } else {
        // ---------------- fold small weights ----------------
        const int t = tid;
        if (t < HD) {
            float l0 = 0, l1 = 0, l2 = 0, r0 = 0, r1 = 0, r2 = 0;
            for (int c = 0; c < HD; ++c) {
                const float w0 = Wd[c * 3 + 0], w1 = Wd[c * 3 + 1], w2 = Wd[c * 3 + 2];
                const float wl = Wl2[t * HD + c];
                const float wr = Wr2[t * HD + c];
                l0 = fmaf(wl, w0, l0); l1 = fmaf(wl, w1, l1); l2 = fmaf(wl, w2, l2);
                r0 = fmaf(wr, w0, r0); r1 = fmaf(wr, w1, r1); r2 = fmaf(wr, w2, r2);
            }
            wsm[t]       = make_float4(l0, l1, l2, 0.f);
            wsm[128 + t] = make_float4(r0, r1, r2, 0.f);
            if (t == 0) {
                float c0 = bd[0], c1 = bd[1], c2 = bd[2];
                for (int c = 0; c < HD; ++c) {
                    c0 = fmaf(b2[c], Wd[c * 3 + 0], c0);
                    c1 = fmaf(b2[c], Wd[c * 3 + 1], c1);
                    c2 = fmaf(b2[c], Wd[c * 3 + 2], c2);
                }
                wsm[256] = make_float4(c0, c1, c2, 0.f);
            }
        }
    }
}

// ---------------------------------------------------------------------------
// K2: one 64-lane wave per row i (cols 2*lane, 2*lane+1):
//   h = relu(mean_j xl[j,:] + xr[i,:] + b1)   (in registers)
//   u[i] = h @ Wld, v[i] = h @ Wrd            (butterfly-reduced 3-vectors)
// Neighbor list staged in LDS -> uniform broadcast reads, 4 gathers in flight.
// ---------------------------------------------------------------------------
__global__ __launch_bounds__(256) void k_agg_proj(
    const float* __restrict__ xl, const float* __restrict__ xr,
    const float* __restrict__ b1, const int* __restrict__ nbr,
    const int* __restrict__ degi, const float* __restrict__ degf,
    const float4* __restrict__ wsm, float4* __restrict__ u4,
    float4* __restrict__ v4)
{
    __shared__ int lists[4][CAP];
    const int w = threadIdx.x >> 6, lane = threadIdx.x & 63;
    const int i = blockIdx.x * 4 + w;
    const int d = degi[i];
    const float inv = 1.0f / degf[i];
    const int* glst = nbr + (size_t)i * CAP;
    if (lane < d)      lists[w][lane]      = glst[lane];
    if (lane + 64 < d) lists[w][lane + 64] = glst[lane + 64];
    // wave-local producer/consumer: lgkmcnt ordering within the wave suffices
    const int* lst = lists[w];

    float s0 = 0.f, s1 = 0.f;
    int t = 0;
    for (; t + 4 <= d; t += 4) {
        const int j0 = lst[t], j1 = lst[t + 1], j2 = lst[t + 2], j3 = lst[t + 3];
        const float2 a0 = ((const float2*)(xl + (size_t)j0 * HD))[lane];
        const float2 a1 = ((const float2*)(xl + (size_t)j1 * HD))[lane];
        const float2 a2 = ((const float2*)(xl + (size_t)j2 * HD))[lane];
        const float2 a3 = ((const float2*)(xl + (size_t)j3 * HD))[lane];
        s0 += a0.x + a1.x + a2.x + a3.x;
        s1 += a0.y + a1.y + a2.y + a3.y;
    }
    for (; t < d; ++t) {
        const float2 a0 = ((const float2*)(xl + (size_t)lst[t] * HD))[lane];
        s0 += a0.x; s1 += a0.y;
    }

    const float2 rr = ((const float2*)(xr + (size_t)i * HD))[lane];
    const float2 bb = ((const float2*)b1)[lane];
    const float h0 = fmaxf(fmaf(s0, inv, rr.x + bb.x), 0.f);
    const float h1 = fmaxf(fmaf(s1, inv, rr.y + bb.y), 0.f);
    const float4 w0 = wsm[2 * lane], w1 = wsm[2 * lane + 1];
    const float4 q0 = wsm[128 + 2 * lane], q1 = wsm[128 + 2 * lane + 1];
    float u0 = h0 * w0.x + h1 * w1.x;
    float u1 = h0 * w0.y + h1 * w1.y;
    float u2 = h0 * w0.z + h1 * w1.z;
    float v0 = h0 * q0.x + h1 * q1.x;
    float v1 = h0 * q0.y + h1 * q1.y;
    float v2 = h0 * q0.z + h1 * q1.z;
    #pragma unroll
    for (int off = 32; off; off >>= 1) {
        u0 += __shfl_xor(u0, off); u1 += __shfl_xor(u1, off); u2 += __shfl_xor(u2, off);
        v0 += __shfl_xor(v0, off); v1 += __shfl_xor(v1, off); v2 += __shfl_xor(v2, off);
    }
    if (lane == 0) {
        u4[i] = make_float4(u0, u1, u2, 0.f);
        v4[i] = make_float4(v0, v1, v2, 0.f);
    }
}

// ---------------------------------------------------------------------------
// K3: y[i] = mean_j u[j] + v[i] + c   (3-wide second-hop aggregation)
// ---------------------------------------------------------------------------
__global__ __launch_bounds__(256) void k_ycomb(
    const float4* __restrict__ u4, const float4* __restrict__ v4,
    const int* __restrict__ nbr, const int* __restrict__ degi,
    const float* __restrict__ degf, const float4* __restrict__ wsm,
    float4* __restrict__ y4)
{
    const int hw = threadIdx.x >> 5;
    const int lane = threadIdx.x & 31;
    const int i = blockIdx.x * 8 + hw;
    const int d = degi[i];
    const float inv = 1.0f / degf[i];
    const int* lst = nbr + (size_t)i * CAP;
    float s0 = 0.f, s1 = 0.f, s2 = 0.f;
    for (int base = 0; base + lane < d; base += 32) {
        const float4 u = u4[lst[base + lane]];
        s0 += u.x; s1 += u.y; s2 += u.z;
    }
    #pragma unroll
    for (int off = 16; off; off >>= 1) {
        s0 += __shfl_xor(s0, off); s1 += __shfl_xor(s1, off); s2 += __shfl_xor(s2, off);
    }
    if (lane == 0) {
        const float4 v = v4[i];
        const float4 c = wsm[256];
        y4[i] = make_float4(fmaf(s0, inv, v.x + c.x),
                            fmaf(s1, inv, v.y + c.y),
                            fmaf(s2, inv, v.z + c.z), 0.f);
    }
}

// ---------------------------------------------------------------------------
// K4: out[i,j] = ||y_i - y_j||, tiled 32 i x 1024 j per block.
// yi staged in LDS (broadcast reads), 4 yj in registers, float4 stores.
// ---------------------------------------------------------------------------
__global__ __launch_bounds__(256) void k_cdist(
    const float4* __restrict__ y4, float* __restrict__ out)
{
    __shared__ float4 yis[32];
    const int t = threadIdx.x;
    const int i0 = blockIdx.y * 32;
    if (t < 32) yis[t] = y4[i0 + t];
    __syncthreads();
    const int j0 = blockIdx.x * 1024 + t * 4;
    const float4 a0 = y4[j0 + 0], a1 = y4[j0 + 1];
    const float4 a2 = y4[j0 + 2], a3 = y4[j0 + 3];
    float* op = out + (size_t)i0 * NN + j0;
    #pragma unroll 4
    for (int ii = 0; ii < 32; ++ii) {
        const float4 yi = yis[ii];
        float4 r;
        { const float dx = yi.x - a0.x, dy = yi.y - a0.y, dz = yi.z - a0.z;
          r.x = sqrtf(fmaf(dx, dx, fmaf(dy, dy, dz * dz))); }
        { const float dx = yi.x - a1.x, dy = yi.y - a1.y, dz = yi.z - a1.z;
          r.y = sqrtf(fmaf(dx, dx, fmaf(dy, dy, dz * dz))); }
        { const float dx = yi.x - a2.x, dy = yi.y - a2.y, dz = yi.z - a2.z;
          r.z = sqrtf(fmaf(dx, dx, fmaf(dy, dy, dz * dz))); }
        { const float dx = yi.x - a3.x, dy = yi.y - a3.y, dz = yi.z - a3.z;
          r.w = sqrtf(fmaf(dx, dx, fmaf(dy, dy, dz * dz))); }
        *(float4*)op = r;
        op += NN;
    }
}

// ---------------------------------------------------------------------------
extern "C" void kernel_launch(void* const* d_in, const int* in_sizes, int n_in,
                              void* d_out, int out_size, void* d_ws, size_t ws_size,
                              hipStream_t stream) {
    const float* x   = (const float*)d_in[0];
    const float* adj = (const float*)d_in[1];
    const float* Wl1 = (const float*)d_in[2];
    const float* Wr1 = (const float*)d_in[3];
    const float* b1  = (const float*)d_in[4];
    const float* Wl2 = (const float*)d_in[5];
    const float* Wr2 = (const float*)d_in[6];
    const float* b2  = (const float*)d_in[7];
    const float* Wd  = (const float*)d_in[8];
    const float* bd  = (const float*)d_in[9];
    float* out = (float*)d_out;

    // ---- workspace layout (16B-aligned slots) ----
    char* ws = (char*)d_ws;
    const size_t nbr_b  = (size_t)NN * CAP * 4;    // 4 MB
    const size_t deg_b  = (size_t)NN * 4;          // 32 KB each
    const size_t vec_b  = (size_t)NN * 16;         // 128 KB each (u4,v4,y4)
    const size_t wsm_b  = 272 * 16;
    const size_t small_total = nbr_b + 2 * deg_b + 3 * vec_b + wsm_b;
    const size_t xl_b = (size_t)NN * HD * 4;       // 4 MB each

    size_t off = 0;
    int*    nbr  = (int*)(ws + off);    off += nbr_b;
    int*    degi = (int*)(ws + off);    off += deg_b;
    float*  degf = (float*)(ws + off);  off += deg_b;
    float4* u4   = (float4*)(ws + off); off += vec_b;
    float4* v4   = (float4*)(ws + off); off += vec_b;
    float4* y4   = (float4*)(ws + off); off += vec_b;
    float4* wsm  = (float4*)(ws + off); off += wsm_b;

    // xl/xr: in ws if it fits, else carve from d_out (dead before k_cdist).
    char* big = (ws_size >= small_total + 2 * xl_b) ? (ws + off) : (char*)d_out;
    float* xl = (float*)(big);
    float* xr = (float*)(big + xl_b);

    // ---- pipeline ----
    k_front<<<GEMM_B + ADJ_B + 1, 256, 0, stream>>>(
        x, Wl1, Wr1, adj, Wl2, Wr2, b2, Wd, bd,
        xl, xr, nbr, degi, degf, wsm);

    k_agg_proj<<<NN / 4, 256, 0, stream>>>(xl, xr, b1, nbr, degi, degf,
                                           wsm, u4, v4);

    k_ycomb<<<NN / 8, 256, 0, stream>>>(u4, v4, nbr, degi, degf, wsm, y4);

    k_cdist<<<dim3(NN / 1024, NN / 32), 256, 0, stream>>>(y4, out);
}